// Round 1
// baseline (1115.414 us; speedup 1.0000x reference)
//
#include <hip/hip_runtime.h>
#include <cstdint>
#include <cstddef>

#define Bc 2
#define Sc 2048
#define Ec 1024
#define Hc 16
#define Dc 64
#define BSc 4096   // B*S
#define BHc 32     // B*H

typedef __attribute__((ext_vector_type(8))) short bf16x8;
typedef __attribute__((ext_vector_type(4))) float f32x4;

__device__ __forceinline__ uint16_t f2b(float x) {
  union { float f; uint32_t u; } v; v.f = x;
  return (uint16_t)((v.u + 0x7FFFu + ((v.u >> 16) & 1u)) >> 16);
}

__device__ __forceinline__ uint4 pack8(const float* f) {
  union { uint16_t u[8]; uint4 v; } pk;
#pragma unroll
  for (int i = 0; i < 8; i++) pk.u[i] = f2b(f[i]);
  return pk.v;
}

// ---------------- prep: fp32 -> bf16 cast ----------------
__global__ void conv_bf16(const float* __restrict__ src, uint16_t* __restrict__ dst, int n) {
  int i = (blockIdx.x * blockDim.x + threadIdx.x) * 4;
  if (i < n) {
    float4 v = *(const float4*)(src + i);
    ushort4 o;
    o.x = f2b(v.x); o.y = f2b(v.y); o.z = f2b(v.z); o.w = f2b(v.w);
    *(ushort4*)(dst + i) = o;
  }
}

// ---------------- prep: W (K x N fp32) -> WT (N x K bf16) ----------------
__global__ void transpose_bf16(const float* __restrict__ src, uint16_t* __restrict__ dst) {
  __shared__ uint16_t tile[32][33];
  int x0 = blockIdx.x * 32, y0 = blockIdx.y * 32;
  int tx = threadIdx.x & 31, ty = threadIdx.x >> 5;  // 256 thr: ty 0..7
#pragma unroll
  for (int i = 0; i < 32; i += 8)
    tile[ty + i][tx] = f2b(src[(size_t)(y0 + ty + i) * 1024 + x0 + tx]);
  __syncthreads();
#pragma unroll
  for (int i = 0; i < 32; i += 8)
    dst[(size_t)(x0 + ty + i) * 1024 + y0 + tx] = tile[tx][ty + i];
}

// ---------------- QKV projection GEMM ----------------
// A: M x K bf16 (M=4096,K=1024), BT: N x K bf16 (N=1024), bias fp32[N]
// mode 0: out[b][h][s][d]   mode 1: out[b][h][d][s]  (vT)
__global__ __launch_bounds__(256) void gemm_proj(
    const uint16_t* __restrict__ A, const uint16_t* __restrict__ BT,
    const float* __restrict__ bias, uint16_t* __restrict__ out, int mode) {
  const int K = 1024;
  __shared__ uint16_t As[128 * 40];
  __shared__ uint16_t Bs[128 * 40];
  int n0 = blockIdx.x * 128, m0 = blockIdx.y * 128;
  int t = threadIdx.x;
  int wave = t >> 6, lane = t & 63;
  int wm = (wave >> 1) * 64, wn = (wave & 1) * 64;
  int quad = lane >> 4, l16 = lane & 15;

  f32x4 acc[4][4];
#pragma unroll
  for (int i = 0; i < 4; i++)
#pragma unroll
    for (int j = 0; j < 4; j++) acc[i][j] = (f32x4)(0.0f);

  int srow = t >> 1, scol = (t & 1) * 16;  // thread loads 32B of a 64B tile-row

  for (int k0 = 0; k0 < K; k0 += 32) {
    const uint16_t* ag = A + (size_t)(m0 + srow) * K + k0 + scol;
    const uint16_t* bg = BT + (size_t)(n0 + srow) * K + k0 + scol;
    uint4 av0 = *(const uint4*)ag;
    uint4 av1 = *(const uint4*)(ag + 8);
    uint4 bv0 = *(const uint4*)bg;
    uint4 bv1 = *(const uint4*)(bg + 8);
    __syncthreads();
    *(uint4*)(As + srow * 40 + scol) = av0;
    *(uint4*)(As + srow * 40 + scol + 8) = av1;
    *(uint4*)(Bs + srow * 40 + scol) = bv0;
    *(uint4*)(Bs + srow * 40 + scol + 8) = bv1;
    __syncthreads();
    bf16x8 af[4], bfr[4];
#pragma unroll
    for (int i = 0; i < 4; i++)
      af[i] = *(const bf16x8*)(As + (wm + i * 16 + l16) * 40 + quad * 8);
#pragma unroll
    for (int j = 0; j < 4; j++)
      bfr[j] = *(const bf16x8*)(Bs + (wn + j * 16 + l16) * 40 + quad * 8);
#pragma unroll
    for (int i = 0; i < 4; i++)
#pragma unroll
      for (int j = 0; j < 4; j++)
        acc[i][j] = __builtin_amdgcn_mfma_f32_16x16x32_bf16(af[i], bfr[j], acc[i][j], 0, 0, 0);
  }
#pragma unroll
  for (int i = 0; i < 4; i++)
#pragma unroll
    for (int j = 0; j < 4; j++) {
      int col = n0 + wn + j * 16 + l16;
      float bval = bias[col];
      int h = col >> 6, d = col & 63;
#pragma unroll
      for (int r = 0; r < 4; r++) {
        int row = m0 + wm + i * 16 + quad * 4 + r;
        int b = row >> 11, s = row & 2047;
        uint16_t hv = f2b(acc[i][j][r] + bval);
        if (mode == 0)
          out[(size_t)((b * Hc + h) * Sc + s) * Dc + d] = hv;
        else
          out[(size_t)((b * Hc + h) * Dc + d) * Sc + s] = hv;
      }
    }
}

// ---------------- output projection GEMM + bias + residual ----------------
__global__ __launch_bounds__(256) void gemm_out(
    const uint16_t* __restrict__ A, const uint16_t* __restrict__ BT,
    const float* __restrict__ bias, const float* __restrict__ resid,
    float* __restrict__ x) {
  const int K = 1024;
  __shared__ uint16_t As[128 * 40];
  __shared__ uint16_t Bs[128 * 40];
  int n0 = blockIdx.x * 128, m0 = blockIdx.y * 128;
  int t = threadIdx.x;
  int wave = t >> 6, lane = t & 63;
  int wm = (wave >> 1) * 64, wn = (wave & 1) * 64;
  int quad = lane >> 4, l16 = lane & 15;

  f32x4 acc[4][4];
#pragma unroll
  for (int i = 0; i < 4; i++)
#pragma unroll
    for (int j = 0; j < 4; j++) acc[i][j] = (f32x4)(0.0f);

  int srow = t >> 1, scol = (t & 1) * 16;
  for (int k0 = 0; k0 < K; k0 += 32) {
    const uint16_t* ag = A + (size_t)(m0 + srow) * K + k0 + scol;
    const uint16_t* bg = BT + (size_t)(n0 + srow) * K + k0 + scol;
    uint4 av0 = *(const uint4*)ag;
    uint4 av1 = *(const uint4*)(ag + 8);
    uint4 bv0 = *(const uint4*)bg;
    uint4 bv1 = *(const uint4*)(bg + 8);
    __syncthreads();
    *(uint4*)(As + srow * 40 + scol) = av0;
    *(uint4*)(As + srow * 40 + scol + 8) = av1;
    *(uint4*)(Bs + srow * 40 + scol) = bv0;
    *(uint4*)(Bs + srow * 40 + scol + 8) = bv1;
    __syncthreads();
    bf16x8 af[4], bfr[4];
#pragma unroll
    for (int i = 0; i < 4; i++)
      af[i] = *(const bf16x8*)(As + (wm + i * 16 + l16) * 40 + quad * 8);
#pragma unroll
    for (int j = 0; j < 4; j++)
      bfr[j] = *(const bf16x8*)(Bs + (wn + j * 16 + l16) * 40 + quad * 8);
#pragma unroll
    for (int i = 0; i < 4; i++)
#pragma unroll
      for (int j = 0; j < 4; j++)
        acc[i][j] = __builtin_amdgcn_mfma_f32_16x16x32_bf16(af[i], bfr[j], acc[i][j], 0, 0, 0);
  }
#pragma unroll
  for (int i = 0; i < 4; i++)
#pragma unroll
    for (int j = 0; j < 4; j++) {
      int col = n0 + wn + j * 16 + l16;
      float bval = bias[col];
#pragma unroll
      for (int r = 0; r < 4; r++) {
        int row = m0 + wm + i * 16 + quad * 4 + r;
        x[(size_t)row * 1024 + col] = acc[i][j][r] + bval + resid[(size_t)row * 1024 + col];
      }
    }
}

// ---------------- scores: exp(QK^T/8 masked) + partial rowsums ----------------
__global__ __launch_bounds__(256) void scores_kernel(
    const uint16_t* __restrict__ q,  // [BH,S,64]
    const uint16_t* __restrict__ k,  // [BH,S,64]
    const int* __restrict__ mask,    // [B,S,S] int32 (true -> masked)
    float* __restrict__ attn,        // [BH,S,S] <- exp (unnormalized)
    float* __restrict__ rowsum) {    // [BH,S]
  __shared__ uint16_t Qs[128 * 72];
  __shared__ uint16_t Ks[128 * 72];
  int n0 = blockIdx.x * 128, m0 = blockIdx.y * 128;
  int bh = blockIdx.z;
  int b = bh >> 4;
  int t = threadIdx.x;
  int wave = t >> 6, lane = t & 63;
  int wm = (wave >> 1) * 64, wn = (wave & 1) * 64;
  int quad = lane >> 4, l16 = lane & 15;

  // stage q,k tiles: 128 rows x 64 bf16, thread loads 64B (4 x uint4)
  int srow = t >> 1, scol = (t & 1) * 32;
  {
    const uint16_t* qg = q + (size_t)(bh * Sc + m0 + srow) * Dc + scol;
    const uint16_t* kg = k + (size_t)(bh * Sc + n0 + srow) * Dc + scol;
#pragma unroll
    for (int c = 0; c < 4; c++)
      *(uint4*)(Qs + srow * 72 + scol + c * 8) = *(const uint4*)(qg + c * 8);
#pragma unroll
    for (int c = 0; c < 4; c++)
      *(uint4*)(Ks + srow * 72 + scol + c * 8) = *(const uint4*)(kg + c * 8);
  }
  __syncthreads();

  f32x4 acc[4][4];
#pragma unroll
  for (int i = 0; i < 4; i++)
#pragma unroll
    for (int j = 0; j < 4; j++) acc[i][j] = (f32x4)(0.0f);

#pragma unroll
  for (int kk = 0; kk < 2; kk++) {
    bf16x8 af[4], bfr[4];
#pragma unroll
    for (int i = 0; i < 4; i++)
      af[i] = *(const bf16x8*)(Qs + (wm + i * 16 + l16) * 72 + kk * 32 + quad * 8);
#pragma unroll
    for (int j = 0; j < 4; j++)
      bfr[j] = *(const bf16x8*)(Ks + (wn + j * 16 + l16) * 72 + kk * 32 + quad * 8);
#pragma unroll
    for (int i = 0; i < 4; i++)
#pragma unroll
      for (int j = 0; j < 4; j++)
        acc[i][j] = __builtin_amdgcn_mfma_f32_16x16x32_bf16(af[i], bfr[j], acc[i][j], 0, 0, 0);
  }

#pragma unroll
  for (int i = 0; i < 4; i++) {
#pragma unroll
    for (int r = 0; r < 4; r++) {
      int m = m0 + wm + i * 16 + quad * 4 + r;
      const int* mrow = mask + (size_t)(b * Sc + m) * Sc;
      float* arow = attn + ((size_t)(bh * Sc + m)) * Sc;
      float rs = 0.0f;
#pragma unroll
      for (int j = 0; j < 4; j++) {
        int n = n0 + wn + j * 16 + l16;
        float sc = acc[i][j][r] * 0.125f;
        float p = mrow[n] ? 0.0f : __expf(sc);
        arow[n] = p;
        rs += p;
      }
      rs += __shfl_xor(rs, 1);
      rs += __shfl_xor(rs, 2);
      rs += __shfl_xor(rs, 4);
      rs += __shfl_xor(rs, 8);
      if (l16 == 0) atomicAdd(&rowsum[bh * Sc + m], rs);
    }
  }
}

__global__ void inv_kernel(const float* __restrict__ rowsum, float* __restrict__ rowinv, int n) {
  int i = blockIdx.x * blockDim.x + threadIdx.x;
  if (i < n) rowinv[i] = 1.0f / rowsum[i];
}

// ---------------- context: normalize attn (writeback) + attn @ V ----------------
__global__ __launch_bounds__(256) void context_kernel(
    float* __restrict__ attn,         // [BH,S,S] exp in -> normalized out
    const float* __restrict__ rowinv, // [BH,S]
    const uint16_t* __restrict__ vT,  // [BH,64,S]
    uint16_t* __restrict__ ctx) {     // [B,S,H*64]
  __shared__ uint16_t As[64 * 72];
  __shared__ uint16_t Vs[64 * 72];
  int m0 = blockIdx.x * 64;
  int bh = blockIdx.y;
  int t = threadIdx.x;
  int wave = t >> 6, lane = t & 63;
  int quad = lane >> 4, l16 = lane & 15;

  f32x4 acc[4];
#pragma unroll
  for (int j = 0; j < 4; j++) acc[j] = (f32x4)(0.0f);

  int arow = t >> 2, acol = (t & 3) * 16;  // 64 rows x 64 fp32, 16 floats/thread
  float inv_r = rowinv[bh * Sc + m0 + arow];
  int vrow = t >> 2, vcol = (t & 3) * 16;  // 64 rows x 64 bf16, 16 bf16/thread

  for (int k0 = 0; k0 < Sc; k0 += 64) {
    float* ag = attn + ((size_t)(bh * Sc + m0 + arow)) * Sc + k0 + acol;
    float va[16];
    float4 a0 = *(const float4*)ag;
    float4 a1 = *(const float4*)(ag + 4);
    float4 a2 = *(const float4*)(ag + 8);
    float4 a3 = *(const float4*)(ag + 12);
    va[0] = a0.x * inv_r;  va[1] = a0.y * inv_r;  va[2] = a0.z * inv_r;  va[3] = a0.w * inv_r;
    va[4] = a1.x * inv_r;  va[5] = a1.y * inv_r;  va[6] = a1.z * inv_r;  va[7] = a1.w * inv_r;
    va[8] = a2.x * inv_r;  va[9] = a2.y * inv_r;  va[10] = a2.z * inv_r; va[11] = a2.w * inv_r;
    va[12] = a3.x * inv_r; va[13] = a3.y * inv_r; va[14] = a3.z * inv_r; va[15] = a3.w * inv_r;
    // write normalized attn back (this is the graded attn output)
    float4 w0 = make_float4(va[0], va[1], va[2], va[3]);
    float4 w1 = make_float4(va[4], va[5], va[6], va[7]);
    float4 w2 = make_float4(va[8], va[9], va[10], va[11]);
    float4 w3 = make_float4(va[12], va[13], va[14], va[15]);
    *(float4*)ag = w0;
    *(float4*)(ag + 4) = w1;
    *(float4*)(ag + 8) = w2;
    *(float4*)(ag + 12) = w3;
    const uint16_t* vg = vT + ((size_t)(bh * Dc + vrow)) * Sc + k0 + vcol;
    uint4 vv0 = *(const uint4*)vg;
    uint4 vv1 = *(const uint4*)(vg + 8);
    __syncthreads();
    *(uint4*)(As + arow * 72 + acol) = pack8(va);
    *(uint4*)(As + arow * 72 + acol + 8) = pack8(va + 8);
    *(uint4*)(Vs + vrow * 72 + vcol) = vv0;
    *(uint4*)(Vs + vrow * 72 + vcol + 8) = vv1;
    __syncthreads();
#pragma unroll
    for (int kk = 0; kk < 2; kk++) {
      bf16x8 af = *(const bf16x8*)(As + (wave * 16 + l16) * 72 + kk * 32 + quad * 8);
#pragma unroll
      for (int j = 0; j < 4; j++) {
        bf16x8 bfr = *(const bf16x8*)(Vs + (j * 16 + l16) * 72 + kk * 32 + quad * 8);
        acc[j] = __builtin_amdgcn_mfma_f32_16x16x32_bf16(af, bfr, acc[j], 0, 0, 0);
      }
    }
    __syncthreads();
  }
  int b = bh >> 4, h = bh & 15;
#pragma unroll
  for (int j = 0; j < 4; j++) {
    int d = j * 16 + l16;
#pragma unroll
    for (int r = 0; r < 4; r++) {
      int s = m0 + wave * 16 + quad * 4 + r;
      ctx[(size_t)(b * Sc + s) * (Hc * Dc) + h * Dc + d] = f2b(acc[j][r]);
    }
  }
}

// ---------------- LayerNorm ----------------
__global__ __launch_bounds__(256) void ln_kernel(
    const float* __restrict__ x, const float* __restrict__ gamma,
    const float* __restrict__ beta, float* __restrict__ y) {
  int row = blockIdx.x;
  int t = threadIdx.x;
  const float* xr = x + (size_t)row * 1024;
  float4 v = *(const float4*)(xr + t * 4);
  float s = v.x + v.y + v.z + v.w;
  float s2 = v.x * v.x + v.y * v.y + v.z * v.z + v.w * v.w;
#pragma unroll
  for (int o = 1; o < 64; o <<= 1) {
    s += __shfl_xor(s, o);
    s2 += __shfl_xor(s2, o);
  }
  __shared__ float ss[4], ss2[4];
  int wave = t >> 6, lane = t & 63;
  if (lane == 0) { ss[wave] = s; ss2[wave] = s2; }
  __syncthreads();
  s = ss[0] + ss[1] + ss[2] + ss[3];
  s2 = ss2[0] + ss2[1] + ss2[2] + ss2[3];
  float mu = s * (1.0f / 1024.0f);
  float var = s2 * (1.0f / 1024.0f) - mu * mu;
  float rstd = rsqrtf(var + 1e-5f);
  float4 g = *(const float4*)(gamma + t * 4);
  float4 be = *(const float4*)(beta + t * 4);
  float4 o;
  o.x = (v.x - mu) * rstd * g.x + be.x;
  o.y = (v.y - mu) * rstd * g.y + be.y;
  o.z = (v.z - mu) * rstd * g.z + be.z;
  o.w = (v.w - mu) * rstd * g.w + be.w;
  *(float4*)(y + (size_t)row * 1024 + t * 4) = o;
}

extern "C" void kernel_launch(void* const* d_in, const int* in_sizes, int n_in,
                              void* d_out, int out_size, void* d_ws, size_t ws_size,
                              hipStream_t stream) {
  const float* Q = (const float*)d_in[0];
  const float* K = (const float*)d_in[1];
  const float* V = (const float*)d_in[2];
  const int* mask = (const int*)d_in[3];
  const float* Wq = (const float*)d_in[4];
  const float* bq = (const float*)d_in[5];
  const float* Wk = (const float*)d_in[6];
  const float* bk = (const float*)d_in[7];
  const float* Wv = (const float*)d_in[8];
  const float* bv = (const float*)d_in[9];
  const float* Wo = (const float*)d_in[10];
  const float* bo = (const float*)d_in[11];
  const float* gamma = (const float*)d_in[12];
  const float* beta = (const float*)d_in[13];

  float* y = (float*)d_out;                           // [B,S,E]
  float* attn = (float*)d_out + (size_t)BSc * Ec;     // [B,H,S,S]

  char* ws = (char*)d_ws;
  size_t off = 0;
  auto alloc = [&](size_t bytes) -> void* {
    void* p = ws + off;
    off = (off + bytes + 255) & ~(size_t)255;
    return p;
  };
  uint16_t* Qb  = (uint16_t*)alloc((size_t)BSc * Ec * 2);
  uint16_t* Kb  = (uint16_t*)alloc((size_t)BSc * Ec * 2);
  uint16_t* Vb  = (uint16_t*)alloc((size_t)BSc * Ec * 2);
  uint16_t* WqT = (uint16_t*)alloc((size_t)Ec * Ec * 2);
  uint16_t* WkT = (uint16_t*)alloc((size_t)Ec * Ec * 2);
  uint16_t* WvT = (uint16_t*)alloc((size_t)Ec * Ec * 2);
  uint16_t* WoT = (uint16_t*)alloc((size_t)Ec * Ec * 2);
  uint16_t* qh  = (uint16_t*)alloc((size_t)BHc * Sc * Dc * 2);  // [BH,S,64]
  uint16_t* kh  = (uint16_t*)alloc((size_t)BHc * Sc * Dc * 2);  // [BH,S,64]
  uint16_t* vT  = (uint16_t*)alloc((size_t)BHc * Dc * Sc * 2);  // [BH,64,S]
  uint16_t* ctx = (uint16_t*)alloc((size_t)BSc * Ec * 2);       // [B,S,1024]
  float* xres   = (float*)alloc((size_t)BSc * Ec * 4);
  float* rowsum = (float*)alloc((size_t)BHc * Sc * 4);
  float* rowinv = (float*)alloc((size_t)BHc * Sc * 4);

  const int n_qkv = BSc * Ec;  // 4,194,304

  // 1) casts
  conv_bf16<<<n_qkv / 1024, 256, 0, stream>>>(Q, Qb, n_qkv);
  conv_bf16<<<n_qkv / 1024, 256, 0, stream>>>(K, Kb, n_qkv);
  conv_bf16<<<n_qkv / 1024, 256, 0, stream>>>(V, Vb, n_qkv);
  // 2) weight transposes
  dim3 tg(32, 32);
  transpose_bf16<<<tg, 256, 0, stream>>>(Wq, WqT);
  transpose_bf16<<<tg, 256, 0, stream>>>(Wk, WkT);
  transpose_bf16<<<tg, 256, 0, stream>>>(Wv, WvT);
  transpose_bf16<<<tg, 256, 0, stream>>>(Wo, WoT);
  // 3) QKV projections
  dim3 pg(Ec / 128, BSc / 128);  // (8, 32)
  gemm_proj<<<pg, 256, 0, stream>>>(Qb, WqT, bq, qh, 0);
  gemm_proj<<<pg, 256, 0, stream>>>(Kb, WkT, bk, kh, 0);
  gemm_proj<<<pg, 256, 0, stream>>>(Vb, WvT, bv, vT, 1);
  // 4) scores -> exp + rowsums
  hipMemsetAsync(rowsum, 0, (size_t)BHc * Sc * 4, stream);
  dim3 sg(Sc / 128, Sc / 128, BHc);  // (16,16,32)
  scores_kernel<<<sg, 256, 0, stream>>>(qh, kh, mask, attn, rowsum);
  inv_kernel<<<(BHc * Sc) / 256, 256, 0, stream>>>(rowsum, rowinv, BHc * Sc);
  // 5) normalize (writeback) + PV
  dim3 cg(Sc / 64, BHc);  // (32, 32)
  context_kernel<<<cg, 256, 0, stream>>>(attn, rowinv, vT, ctx);
  // 6) out projection + residual
  gemm_out<<<pg, 256, 0, stream>>>(ctx, WoT, bo, Q, xres);
  // 7) LayerNorm
  ln_kernel<<<BSc, 256, 0, stream>>>(xres, gamma, beta, y);
}